// Round 4
// baseline (242.130 us; speedup 1.0000x reference)
//
#include <hip/hip_runtime.h>
#include <hip/hip_bf16.h>
#include <math.h>

// SAGAN attention block. Inputs/outputs fp32; internal matmuls bf16 MFMA.
// B=8, N=4096 (64x64 spatial), C=512, D=64.

typedef short v8s __attribute__((ext_vector_type(8)));
typedef unsigned short v4u __attribute__((ext_vector_type(4)));
typedef float v4f __attribute__((ext_vector_type(4)));

#define BB 8
#define NN 4096
#define CC 512
#define DD 64

__device__ __forceinline__ unsigned short f2bf(float f){
  union { float f; unsigned u; } v; v.f = f;
  unsigned r = (v.u + 0x7FFF + ((v.u >> 16) & 1)) >> 16;
  return (unsigned short)r;
}

// async global->LDS, 16B per lane; LDS dest = wave-uniform base + lane*16
__device__ __forceinline__ void gload_lds16(const void* g, void* l){
  __builtin_amdgcn_global_load_lds(
      (const __attribute__((address_space(1))) void*)g,
      (__attribute__((address_space(3))) void*)l, 16, 0, 0);
}

// ---------------------------------------------------------------------------
// Kernel 0: convert fp32 weights to bf16, transposed (K-contiguous B-frags).
// ---------------------------------------------------------------------------
__global__ void transpose_w(const float* __restrict__ Wf,
                            const float* __restrict__ Wg,
                            const float* __restrict__ Wh,
                            const float* __restrict__ Wv,
                            unsigned short* __restrict__ Wt,
                            unsigned short* __restrict__ Wvt){
  int idx = blockIdx.x * 256 + threadIdx.x;
  if (idx < 3 * DD * CC){
    int p = idx / (DD * CC); int rem = idx % (DD * CC);
    int d = rem / CC; int c = rem % CC;
    const float* W = (p == 0) ? Wf : ((p == 1) ? Wg : Wh);
    Wt[idx] = f2bf(W[c * DD + d]);
  } else {
    int idx2 = idx - 3 * DD * CC;
    if (idx2 < CC * DD){
      int c = idx2 / DD; int d = idx2 % DD;
      Wvt[idx2] = f2bf(Wv[d * CC + c]);
    }
  }
}

// ---------------------------------------------------------------------------
// Kernel 1: fused projection GEMM.  f|g|h = x @ [Wf|Wg|Wh] + bias.
// f (query) pre-scaled by log2(e) so flash uses native exp2.
// ---------------------------------------------------------------------------
__global__ __launch_bounds__(256) void proj_kernel(
    const float* __restrict__ x,             // [32768][512] fp32
    const unsigned short* __restrict__ Wt,   // [192][512] bf16
    const float* __restrict__ bf_,
    const float* __restrict__ bg_,
    const float* __restrict__ bh_,
    unsigned short* __restrict__ f,
    unsigned short* __restrict__ g,
    unsigned short* __restrict__ ht)
{
  __shared__ __align__(16) short lA[64][72];
  __shared__ __align__(16) short lB[192][72];
  int t = threadIdx.x;
  int w = t >> 6, lane = t & 63;
  int quad = lane >> 4, l16 = lane & 15;
  int rowbase = blockIdx.x * 64;
  int m0 = w * 16;

  v4f acc[12];
  #pragma unroll
  for (int i = 0; i < 12; i++) acc[i] = (v4f){0.f, 0.f, 0.f, 0.f};

  for (int kt = 0; kt < 8; ++kt){
    int k0 = kt * 64;
    #pragma unroll
    for (int r = 0; r < 4; r++){     // A tile: 64 rows x 64 floats -> bf16
      int chunk = t + r * 256;
      int row = chunk >> 4, c4 = chunk & 15;
      v4f xv = *(const v4f*)(x + (rowbase + row) * 512 + k0 + c4 * 4);
      v4u bv4 = { f2bf(xv[0]), f2bf(xv[1]), f2bf(xv[2]), f2bf(xv[3]) };
      *(v4u*)&lA[row][c4 * 4] = bv4;
    }
    #pragma unroll
    for (int r = 0; r < 6; r++){     // B tile: 192x64 bf16
      int chunk = t + r * 256;
      int row = chunk >> 3, c8 = chunk & 7;
      *(v8s*)&lB[row][c8 * 8] = *(const v8s*)(Wt + row * 512 + k0 + c8 * 8);
    }
    __syncthreads();
    v8s A0 = *(const v8s*)&lA[m0 + l16][quad * 8];
    v8s A1 = *(const v8s*)&lA[m0 + l16][quad * 8 + 32];
    #pragma unroll
    for (int cb = 0; cb < 12; ++cb){
      v8s b0 = *(const v8s*)&lB[cb * 16 + l16][quad * 8];
      v8s b1 = *(const v8s*)&lB[cb * 16 + l16][quad * 8 + 32];
      acc[cb] = __builtin_amdgcn_mfma_f32_16x16x32_bf16(A0, b0, acc[cb], 0, 0, 0);
      acc[cb] = __builtin_amdgcn_mfma_f32_16x16x32_bf16(A1, b1, acc[cb], 0, 0, 0);
    }
    __syncthreads();
  }
  #pragma unroll
  for (int cb = 0; cb < 12; ++cb){
    int col = cb * 16 + l16;
    int p = col >> 6, d = col & 63;
    const float* bias = (p == 0) ? bf_ : ((p == 1) ? bg_ : bh_);
    float bb = bias[d];
    #pragma unroll
    for (int r = 0; r < 4; r++){
      int gr = rowbase + m0 + quad * 4 + r;
      float val = acc[cb][r] + bb;
      if (p == 0)      f[gr * 64 + d] = f2bf(val * 1.44269504f);  // log2(e)
      else if (p == 1) g[gr * 64 + d] = f2bf(val);
      else {
        int b = gr >> 12, n = gr & 4095;
        ht[(b * 64 + d) * 4096 + n] = f2bf(val);
      }
    }
  }
}

// ---------------------------------------------------------------------------
// Kernel 2: flash attention, S^T form, no-max softmax (exp2 domain).
// Block = 128 Q rows (4 waves x 32), niter key-tiles of 64.
// K/V tiles: unpadded 64x64 in LDS, 16B-chunk XOR swizzle (c ^= row&7),
// staged via global_load_lds (swizzle folded into the global source addr).
// ---------------------------------------------------------------------------
__global__ __launch_bounds__(256) void flash_kernel(
    const unsigned short* __restrict__ f,   // Q [B][N][64] (prescaled log2e)
    const unsigned short* __restrict__ g,   // K [B][N][64]
    const unsigned short* __restrict__ ht,  // V^T [B][64][N]
    float* __restrict__ Opart,              // [1024][128][64] fp32 (split)
    float* __restrict__ lipart,             // [1024][128]
    unsigned short* __restrict__ ctx,       // [B][N][64] (direct)
    int niter, int direct)
{
  __shared__ __align__(16) short lK[64 * 64];     // [key][d] swizzled
  __shared__ __align__(16) short lV[64 * 64];     // [d][key] swizzled
  __shared__ __align__(16) short lP[4][32][72];   // per-wave [q][key], padded
  int t = threadIdx.x;
  int w = t >> 6, lane = t & 63;
  int quad = lane >> 4, l16 = lane & 15;
  int qt = blockIdx.x, sp = blockIdx.y, b = blockIdx.z;
  int q0 = qt * 128;

  const unsigned short* fb = f  + b * NN * 64;
  const unsigned short* gb = g  + b * NN * 64;
  const unsigned short* hb = ht + b * 64 * NN;

  // Q as B-operand frags, two 16-row groups per wave
  v8s QB[2][2];
  #pragma unroll
  for (int gq = 0; gq < 2; gq++){
    const unsigned short* qp = fb + (q0 + w * 32 + gq * 16 + l16) * 64 + quad * 8;
    QB[gq][0] = *(const v8s*)qp;
    QB[gq][1] = *(const v8s*)(qp + 32);
  }

  // staging: wave w fills LDS bytes [w*2048, w*2048+2048) in 2 calls of 1024B
  int j0 = sp * niter;
  const char* srcK[2]; const char* srcV[2];
  char* dstK[2]; char* dstV[2];
  #pragma unroll
  for (int k = 0; k < 2; k++){
    int row = w * 16 + k * 8 + (lane >> 3);
    int c = (lane & 7) ^ (row & 7);            // XOR swizzle on source
    srcK[k] = (const char*)gb + (size_t)j0 * 8192 + row * 128 + c * 16;
    srcV[k] = (const char*)hb + (size_t)row * 8192 + (size_t)j0 * 128 + c * 16;
    dstK[k] = (char*)lK + w * 2048 + k * 1024;
    dstV[k] = (char*)lV + w * 2048 + k * 1024;
  }

  // loop-invariant LDS frag addresses (logical chunk quad / quad+4)
  int ph = quad ^ (l16 & 7);
  const short* kA0 = lK + l16 * 64 + ph * 8;
  const short* kA1 = lK + l16 * 64 + (ph ^ 4) * 8;
  const short* vB0 = lV + l16 * 64 + ph * 8;
  const short* vB1 = lV + l16 * 64 + (ph ^ 4) * 8;

  float rsum[2] = {0.f, 0.f};
  v4f O[2][4];
  #pragma unroll
  for (int gq = 0; gq < 2; gq++)
    #pragma unroll
    for (int cb = 0; cb < 4; cb++) O[gq][cb] = (v4f){0.f, 0.f, 0.f, 0.f};

  for (int jj = 0; jj < niter; ++jj){
    #pragma unroll
    for (int k = 0; k < 2; k++){
      gload_lds16(srcK[k], dstK[k]);
      gload_lds16(srcV[k], dstV[k]);
      srcK[k] += 8192; srcV[k] += 128;
    }
    __syncthreads();    // drains vmcnt -> tiles ready

    v8s ka[4][2], vb[4][2];
    #pragma unroll
    for (int cb = 0; cb < 4; cb++){
      ka[cb][0] = *(const v8s*)(kA0 + cb * 1024);
      ka[cb][1] = *(const v8s*)(kA1 + cb * 1024);
      vb[cb][0] = *(const v8s*)(vB0 + cb * 1024);
      vb[cb][1] = *(const v8s*)(vB1 + cb * 1024);
    }

    #pragma unroll
    for (int gq = 0; gq < 2; gq++){
      // S^T(64key x 16q) = K · Q^T
      v4f st[4];
      #pragma unroll
      for (int cb = 0; cb < 4; cb++){
        v4f z = (v4f){0.f, 0.f, 0.f, 0.f};
        z = __builtin_amdgcn_mfma_f32_16x16x32_bf16(ka[cb][0], QB[gq][0], z, 0, 0, 0);
        st[cb] = __builtin_amdgcn_mfma_f32_16x16x32_bf16(ka[cb][1], QB[gq][1], z, 0, 0, 0);
      }
      // p = 2^s, pack pairs via perm (bf16 trunc), b64 store to lP
      #pragma unroll
      for (int cb = 0; cb < 4; cb++){
        float p0 = exp2f(st[cb][0]);
        float p1 = exp2f(st[cb][1]);
        float p2 = exp2f(st[cb][2]);
        float p3 = exp2f(st[cb][3]);
        rsum[gq] += (p0 + p1) + (p2 + p3);
        unsigned d0 = __builtin_amdgcn_perm(__float_as_uint(p1), __float_as_uint(p0), 0x07060302u);
        unsigned d1 = __builtin_amdgcn_perm(__float_as_uint(p3), __float_as_uint(p2), 0x07060302u);
        uint2 pk; pk.x = d0; pk.y = d1;
        *(uint2*)&lP[w][gq * 16 + l16][cb * 16 + quad * 4] = pk;
      }
    }

    // P·V for both groups (V frags shared)
    #pragma unroll
    for (int gq = 0; gq < 2; gq++){
      v8s PA0 = *(const v8s*)&lP[w][gq * 16 + l16][quad * 8];
      v8s PA1 = *(const v8s*)&lP[w][gq * 16 + l16][quad * 8 + 32];
      #pragma unroll
      for (int cb = 0; cb < 4; cb++){
        O[gq][cb] = __builtin_amdgcn_mfma_f32_16x16x32_bf16(PA0, vb[cb][0], O[gq][cb], 0, 0, 0);
        O[gq][cb] = __builtin_amdgcn_mfma_f32_16x16x32_bf16(PA1, vb[cb][1], O[gq][cb], 0, 0, 0);
      }
    }
    __syncthreads();    // reads done before next stage overwrites
  }

  #pragma unroll
  for (int gq = 0; gq < 2; gq++){
    rsum[gq] += __shfl_xor(rsum[gq], 16, 64);
    rsum[gq] += __shfl_xor(rsum[gq], 32, 64);
  }

  if (direct){
    #pragma unroll
    for (int gq = 0; gq < 2; gq++){
      float inv[4];
      #pragma unroll
      for (int r = 0; r < 4; r++)
        inv[r] = 1.0f / __shfl(rsum[gq], quad * 4 + r, 64);
      #pragma unroll
      for (int cb = 0; cb < 4; cb++)
        #pragma unroll
        for (int r = 0; r < 4; r++){
          int row = q0 + w * 32 + gq * 16 + quad * 4 + r;
          ctx[(b * NN + row) * 64 + cb * 16 + l16] = f2bf(O[gq][cb][r] * inv[r]);
        }
    }
  } else {
    int bf = (b * 32 + qt) * 4 + sp;
    float* Ob = Opart + (size_t)bf * 8192;
    if (quad == 0){
      lipart[bf * 128 + w * 32 + l16]      = rsum[0];
      lipart[bf * 128 + w * 32 + 16 + l16] = rsum[1];
    }
    #pragma unroll
    for (int gq = 0; gq < 2; gq++)
      #pragma unroll
      for (int cb = 0; cb < 4; cb++)
        #pragma unroll
        for (int r = 0; r < 4; r++)
          Ob[(w * 32 + gq * 16 + quad * 4 + r) * 64 + cb * 16 + l16] = O[gq][cb][r];
  }
}

// ---------------------------------------------------------------------------
// Kernel 2b: combine split-K partials -> bf16 ctx.  float4 per thread.
// ---------------------------------------------------------------------------
__global__ __launch_bounds__(256) void reduce_kernel(
    const float* __restrict__ Opart,
    const float* __restrict__ lipart,
    unsigned short* __restrict__ ctx)
{
  int i4 = blockIdx.x * 256 + threadIdx.x;      // 524288 total (x4 elements)
  int bqt = i4 >> 11;                           // (b*32+qt), 2048 vec4 each
  int rem = (i4 & 2047) << 2;                   // element offset within 8192
  int rl  = rem >> 6;                           // row within 128
  const float* Ob  = Opart  + (size_t)bqt * 4 * 8192;
  const float* lib = lipart + bqt * 4 * 128;
  v4f s = *(const v4f*)(Ob + rem);
  s = s + *(const v4f*)(Ob + 8192  + rem);
  s = s + *(const v4f*)(Ob + 16384 + rem);
  s = s + *(const v4f*)(Ob + 24576 + rem);
  float li = (lib[rl] + lib[128 + rl]) + (lib[256 + rl] + lib[384 + rl]);
  float inv = 1.0f / li;
  v4u o = { f2bf(s[0] * inv), f2bf(s[1] * inv), f2bf(s[2] * inv), f2bf(s[3] * inv) };
  *(v4u*)(ctx + (size_t)bqt * 8192 + rem) = o;
}

// ---------------------------------------------------------------------------
// Kernel 3: out = gamma * ctx @ Wv + bv + x.  M=32768, K=64, N=512.
// ---------------------------------------------------------------------------
__global__ __launch_bounds__(256) void outproj_kernel(
    const unsigned short* __restrict__ ctx,
    const unsigned short* __restrict__ Wvt,  // [512][64] bf16
    const float* __restrict__ bv,
    const float* __restrict__ x,
    const float* __restrict__ gamma_p,
    float* __restrict__ out)
{
  __shared__ __align__(16) short lA[64][72];
  __shared__ __align__(16) short lB[128][72];
  int t = threadIdx.x;
  int w = t >> 6, lane = t & 63;
  int quad = lane >> 4, l16 = lane & 15;
  int rowbase = blockIdx.x * 64;
  int colbase = blockIdx.y * 128;
  float gamma = *gamma_p;

  #pragma unroll
  for (int r = 0; r < 2; r++){
    int chunk = t + r * 256;
    int row = chunk >> 3, c8 = chunk & 7;
    *(v8s*)&lA[row][c8 * 8] = *(const v8s*)(ctx + (rowbase + row) * 64 + c8 * 8);
  }
  #pragma unroll
  for (int r = 0; r < 4; r++){
    int chunk = t + r * 256;
    int row = chunk >> 3, c8 = chunk & 7;
    *(v8s*)&lB[row][c8 * 8] = *(const v8s*)(Wvt + (colbase + row) * 64 + c8 * 8);
  }
  __syncthreads();
  int m0 = w * 16;
  v8s A0 = *(const v8s*)&lA[m0 + l16][quad * 8];
  v8s A1 = *(const v8s*)&lA[m0 + l16][quad * 8 + 32];
  v4f acc[8];
  #pragma unroll
  for (int cb = 0; cb < 8; cb++){
    v8s b0 = *(const v8s*)&lB[cb * 16 + l16][quad * 8];
    v8s b1 = *(const v8s*)&lB[cb * 16 + l16][quad * 8 + 32];
    v4f z = (v4f){0.f, 0.f, 0.f, 0.f};
    z = __builtin_amdgcn_mfma_f32_16x16x32_bf16(A0, b0, z, 0, 0, 0);
    acc[cb] = __builtin_amdgcn_mfma_f32_16x16x32_bf16(A1, b1, z, 0, 0, 0);
  }
  #pragma unroll
  for (int cb = 0; cb < 8; cb++){
    int col = colbase + cb * 16 + l16;
    float bvv = bv[col];
    #pragma unroll
    for (int r = 0; r < 4; r++){
      int gr = rowbase + m0 + quad * 4 + r;
      out[gr * 512 + col] = gamma * acc[cb][r] + bvv + x[gr * 512 + col];
    }
  }
}

// ---------------------------------------------------------------------------
extern "C" void kernel_launch(void* const* d_in, const int* in_sizes, int n_in,
                              void* d_out, int out_size, void* d_ws, size_t ws_size,
                              hipStream_t stream) {
  const float* x   = (const float*)d_in[0];
  const float* Wf  = (const float*)d_in[1];
  const float* bf_ = (const float*)d_in[2];
  const float* Wg  = (const float*)d_in[3];
  const float* bg  = (const float*)d_in[4];
  const float* Wh  = (const float*)d_in[5];
  const float* bh  = (const float*)d_in[6];
  const float* Wv  = (const float*)d_in[7];
  const float* bv  = (const float*)d_in[8];
  const float* gam = (const float*)d_in[9];
  float* out = (float*)d_out;

  // workspace map (bytes):
  //   Wt   @ 0         (196608)
  //   Wvt  @ 196608    (65536)
  //   f    @ 262144    (4194304)
  //   g    @ 4456448   (4194304)
  //   ht   @ 8650752   (4194304)
  //   ctx  @ 12845056  (4194304)
  //   Opart @ 17039360 (33554432)   split-K partials
  //   lipart@ 50593792 (524288)     total 51118080 (~48.8 MiB)
  char* ws = (char*)d_ws;
  unsigned short* Wt  = (unsigned short*)(ws);
  unsigned short* Wvt = (unsigned short*)(ws + 196608);
  unsigned short* f   = (unsigned short*)(ws + 262144);
  unsigned short* g   = (unsigned short*)(ws + 4456448);
  unsigned short* ht  = (unsigned short*)(ws + 8650752);
  unsigned short* ctx = (unsigned short*)(ws + 12845056);
  float* Opart  = (float*)(ws + 17039360);
  float* lipart = (float*)(ws + 50593792);

  transpose_w<<<512, 256, 0, stream>>>(Wf, Wg, Wh, Wv, Wt, Wvt);
  proj_kernel<<<512, 256, 0, stream>>>(x, Wt, bf_, bg, bh, f, g, ht);

  bool split = (ws_size >= (size_t)51118080);
  if (split){
    flash_kernel<<<dim3(32, 4, 8), 256, 0, stream>>>(f, g, ht, Opart, lipart, ctx, 16, 0);
    reduce_kernel<<<2048, 256, 0, stream>>>(Opart, lipart, ctx);
  } else {
    flash_kernel<<<dim3(32, 1, 8), 256, 0, stream>>>(f, g, ht, nullptr, nullptr, ctx, 64, 1);
  }
  outproj_kernel<<<dim3(512, 4), 256, 0, stream>>>(ctx, Wvt, bv, x, gam, out);
}

// Round 5
// 228.939 us; speedup vs baseline: 1.0576x; 1.0576x over previous
//
#include <hip/hip_runtime.h>
#include <hip/hip_bf16.h>
#include <math.h>

// SAGAN attention block. Inputs/outputs fp32; internal matmuls bf16 MFMA.
// B=8, N=4096 (64x64 spatial), C=512, D=64.

typedef short v8s __attribute__((ext_vector_type(8)));
typedef unsigned short v4u __attribute__((ext_vector_type(4)));
typedef unsigned v4i __attribute__((ext_vector_type(4)));
typedef float v4f __attribute__((ext_vector_type(4)));

#define BB 8
#define NN 4096
#define CC 512
#define DD 64

__device__ __forceinline__ unsigned short f2bf(float f){
  union { float f; unsigned u; } v; v.f = f;
  unsigned r = (v.u + 0x7FFF + ((v.u >> 16) & 1)) >> 16;
  return (unsigned short)r;
}

// packed f32x2 -> bf16x2 (low = first arg)
#if __has_builtin(__builtin_amdgcn_cvt_pk_bf16_f32)
typedef __bf16 bf2_t __attribute__((ext_vector_type(2)));
__device__ __forceinline__ unsigned pkbf(float a, float b){
  bf2_t r = __builtin_amdgcn_cvt_pk_bf16_f32(a, b);
  union { bf2_t v; unsigned u; } c; c.v = r; return c.u;
}
#else
__device__ __forceinline__ unsigned pkbf(float a, float b){
  return (unsigned)f2bf(a) | ((unsigned)f2bf(b) << 16);
}
#endif

// async global->LDS, 16B per lane; LDS dest = wave-uniform base + lane*16
__device__ __forceinline__ void gload_lds16(const void* g, void* l){
  __builtin_amdgcn_global_load_lds(
      (const __attribute__((address_space(1))) void*)g,
      (__attribute__((address_space(3))) void*)l, 16, 0, 0);
}

// ---------------------------------------------------------------------------
// Kernel 0: convert fp32 weights to bf16, transposed (K-contiguous B-frags).
// ---------------------------------------------------------------------------
__global__ void transpose_w(const float* __restrict__ Wf,
                            const float* __restrict__ Wg,
                            const float* __restrict__ Wh,
                            const float* __restrict__ Wv,
                            unsigned short* __restrict__ Wt,
                            unsigned short* __restrict__ Wvt){
  int idx = blockIdx.x * 256 + threadIdx.x;
  if (idx < 3 * DD * CC){
    int p = idx / (DD * CC); int rem = idx % (DD * CC);
    int d = rem / CC; int c = rem % CC;
    const float* W = (p == 0) ? Wf : ((p == 1) ? Wg : Wh);
    Wt[idx] = f2bf(W[c * DD + d]);
  } else {
    int idx2 = idx - 3 * DD * CC;
    if (idx2 < CC * DD){
      int c = idx2 / DD; int d = idx2 % DD;
      Wvt[idx2] = f2bf(Wv[d * CC + c]);
    }
  }
}

// ---------------------------------------------------------------------------
// Kernel 1: fused projection GEMM.  f|g|h = x @ [Wf|Wg|Wh] + bias.
// f (query) pre-scaled by log2(e).  x converted fp32->bf16 with packed cvt.
// h written transposed (ht[b][d][n]) through an LDS transpose epilogue.
// ---------------------------------------------------------------------------
__global__ __launch_bounds__(256) void proj_kernel(
    const float* __restrict__ x,             // [32768][512] fp32
    const unsigned short* __restrict__ Wt,   // [192][512] bf16
    const float* __restrict__ bf_,
    const float* __restrict__ bg_,
    const float* __restrict__ bh_,
    unsigned short* __restrict__ f,
    unsigned short* __restrict__ g,
    unsigned short* __restrict__ ht)
{
  __shared__ __align__(16) short lA[64][72];
  __shared__ __align__(16) short lB[192][72];
  int t = threadIdx.x;
  int w = t >> 6, lane = t & 63;
  int quad = lane >> 4, l16 = lane & 15;
  int rowbase = blockIdx.x * 64;
  int m0 = w * 16;

  v4f acc[12];
  #pragma unroll
  for (int i = 0; i < 12; i++) acc[i] = (v4f){0.f, 0.f, 0.f, 0.f};

  int arow = t >> 2, aq4 = t & 3;        // A staging: 16 floats per thread
  for (int kt = 0; kt < 8; ++kt){
    int k0 = kt * 64;
    {
      const float* xp = x + (rowbase + arow) * 512 + k0 + aq4 * 16;
      v4f a0 = *(const v4f*)(xp);
      v4f a1 = *(const v4f*)(xp + 4);
      v4f a2 = *(const v4f*)(xp + 8);
      v4f a3 = *(const v4f*)(xp + 12);
      v4i c0 = { pkbf(a0[0],a0[1]), pkbf(a0[2],a0[3]),
                 pkbf(a1[0],a1[1]), pkbf(a1[2],a1[3]) };
      v4i c1 = { pkbf(a2[0],a2[1]), pkbf(a2[2],a2[3]),
                 pkbf(a3[0],a3[1]), pkbf(a3[2],a3[3]) };
      *(v4i*)&lA[arow][aq4 * 16]     = c0;
      *(v4i*)&lA[arow][aq4 * 16 + 8] = c1;
    }
    #pragma unroll
    for (int r = 0; r < 6; r++){     // B tile: 192x64 bf16
      int chunk = t + r * 256;
      int row = chunk >> 3, c8 = chunk & 7;
      *(v8s*)&lB[row][c8 * 8] = *(const v8s*)(Wt + row * 512 + k0 + c8 * 8);
    }
    __syncthreads();
    v8s A0 = *(const v8s*)&lA[m0 + l16][quad * 8];
    v8s A1 = *(const v8s*)&lA[m0 + l16][quad * 8 + 32];
    #pragma unroll
    for (int cb = 0; cb < 12; ++cb){
      v8s b0 = *(const v8s*)&lB[cb * 16 + l16][quad * 8];
      v8s b1 = *(const v8s*)&lB[cb * 16 + l16][quad * 8 + 32];
      acc[cb] = __builtin_amdgcn_mfma_f32_16x16x32_bf16(A0, b0, acc[cb], 0, 0, 0);
      acc[cb] = __builtin_amdgcn_mfma_f32_16x16x32_bf16(A1, b1, acc[cb], 0, 0, 0);
    }
    __syncthreads();
  }

  // f and g: direct stores (32-B segments)
  #pragma unroll
  for (int cb = 0; cb < 8; ++cb){
    int col = cb * 16 + l16;
    int p = col >> 6, d = col & 63;
    float bb = (p == 0) ? bf_[d] : bg_[d];
    #pragma unroll
    for (int r = 0; r < 4; r++){
      int gr = rowbase + m0 + quad * 4 + r;
      float val = acc[cb][r] + bb;
      if (p == 0) f[gr * 64 + d] = f2bf(val * 1.44269504f);  // log2(e) fold
      else        g[gr * 64 + d] = f2bf(val);
    }
  }

  // h: transpose through LDS (reuse lB), then coalesced 16-B stores
  short (*lT)[65] = (short(*)[65])lB;
  #pragma unroll
  for (int cb = 8; cb < 12; ++cb){
    int d = (cb - 8) * 16 + l16;
    float bb = bh_[d];
    #pragma unroll
    for (int r = 0; r < 4; r++)
      lT[m0 + quad * 4 + r][d] = (short)f2bf(acc[cb][r] + bb);
  }
  __syncthreads();
  {
    int dd = t >> 2, nb = t & 3;
    v8s h0, h1;
    #pragma unroll
    for (int i = 0; i < 8; i++){
      h0[i] = lT[nb * 16 + i][dd];
      h1[i] = lT[nb * 16 + 8 + i][dd];
    }
    int bidx = rowbase >> 12;
    int n0 = (rowbase & 4095) + nb * 16;
    unsigned short* hp = ht + ((size_t)(bidx * 64 + dd)) * 4096 + n0;
    *(v8s*)hp = h0;
    *(v8s*)(hp + 8) = h1;
  }
}

// ---------------------------------------------------------------------------
// Kernel 2: flash attention, S^T form, no-max softmax (exp2 domain).
// Block = 64 Q rows (4 waves x 16), niter key-tiles of 64.
// K/V tiles: unpadded 64x64 in LDS, 16B-chunk XOR swizzle (c ^= row&7),
// staged via global_load_lds (swizzle folded into the global source addr).
// ---------------------------------------------------------------------------
__global__ __launch_bounds__(256) void flash_kernel(
    const unsigned short* __restrict__ f,   // Q [B][N][64] (prescaled log2e)
    const unsigned short* __restrict__ g,   // K [B][N][64]
    const unsigned short* __restrict__ ht,  // V^T [B][64][N]
    float* __restrict__ Opart,              // [2048][64][64] fp32 (split)
    float* __restrict__ lipart,             // [2048][64]
    unsigned short* __restrict__ ctx,       // [B][N][64] (direct)
    int niter, int direct)
{
  __shared__ __align__(16) short lK[64 * 64];     // [key][d] swizzled
  __shared__ __align__(16) short lV[64 * 64];     // [d][key] swizzled
  __shared__ __align__(16) short lP[4][16][72];   // per-wave [q][key], padded
  int t = threadIdx.x;
  int w = t >> 6, lane = t & 63;
  int quad = lane >> 4, l16 = lane & 15;
  int qt = blockIdx.x, sp = blockIdx.y, b = blockIdx.z;
  int q0 = qt * 64;
  int m0 = w * 16;

  const unsigned short* fb = f  + b * NN * 64;
  const unsigned short* gb = g  + b * NN * 64;
  const unsigned short* hb = ht + b * 64 * NN;

  // Q as B-operand fragment (B[k=d][n=q]): lane n=l16=q, k=quad*8+j
  v8s QB0 = *(const v8s*)(fb + (q0 + m0 + l16) * 64 + quad * 8);
  v8s QB1 = *(const v8s*)(fb + (q0 + m0 + l16) * 64 + quad * 8 + 32);

  // staging: wave w fills LDS bytes [w*2048, w*2048+2048) in 2 calls of 1024B
  int j0 = sp * niter;
  const char* srcK[2]; const char* srcV[2];
  char* dstK[2]; char* dstV[2];
  #pragma unroll
  for (int k = 0; k < 2; k++){
    int row = w * 16 + k * 8 + (lane >> 3);
    int c = (lane & 7) ^ (row & 7);            // XOR swizzle on source
    srcK[k] = (const char*)gb + (size_t)j0 * 8192 + row * 128 + c * 16;
    srcV[k] = (const char*)hb + (size_t)row * 8192 + (size_t)j0 * 128 + c * 16;
    dstK[k] = (char*)lK + w * 2048 + k * 1024;
    dstV[k] = (char*)lV + w * 2048 + k * 1024;
  }

  // loop-invariant LDS frag addresses (logical chunk quad / quad+4)
  int ph = quad ^ (l16 & 7);
  const short* kA0 = lK + l16 * 64 + ph * 8;
  const short* kA1 = lK + l16 * 64 + (ph ^ 4) * 8;
  const short* vB0 = lV + l16 * 64 + ph * 8;
  const short* vB1 = lV + l16 * 64 + (ph ^ 4) * 8;

  float rsum = 0.f;
  v4f O[4];
  #pragma unroll
  for (int cb = 0; cb < 4; cb++) O[cb] = (v4f){0.f, 0.f, 0.f, 0.f};

  for (int jj = 0; jj < niter; ++jj){
    #pragma unroll
    for (int k = 0; k < 2; k++){
      gload_lds16(srcK[k], dstK[k]);
      gload_lds16(srcV[k], dstV[k]);
      srcK[k] += 8192; srcV[k] += 128;
    }
    __syncthreads();    // drains vmcnt -> tiles ready

    // S^T(64key x 16q) = K · Q^T : st[cb][r] = S[q=l16][key=cb*16+quad*4+r]
    v4f st[4];
    #pragma unroll
    for (int cb = 0; cb < 4; cb++){
      v8s a0 = *(const v8s*)(kA0 + cb * 1024);
      v8s a1 = *(const v8s*)(kA1 + cb * 1024);
      v4f z = (v4f){0.f, 0.f, 0.f, 0.f};
      z = __builtin_amdgcn_mfma_f32_16x16x32_bf16(a0, QB0, z, 0, 0, 0);
      st[cb] = __builtin_amdgcn_mfma_f32_16x16x32_bf16(a1, QB1, z, 0, 0, 0);
    }

    // p = 2^s, pack pairs via perm (bf16 trunc), b64 store to lP
    #pragma unroll
    for (int cb = 0; cb < 4; cb++){
      float p0 = exp2f(st[cb][0]);
      float p1 = exp2f(st[cb][1]);
      float p2 = exp2f(st[cb][2]);
      float p3 = exp2f(st[cb][3]);
      rsum += (p0 + p1) + (p2 + p3);
      unsigned d0 = __builtin_amdgcn_perm(__float_as_uint(p1), __float_as_uint(p0), 0x07060302u);
      unsigned d1 = __builtin_amdgcn_perm(__float_as_uint(p3), __float_as_uint(p2), 0x07060302u);
      uint2 pk; pk.x = d0; pk.y = d1;
      *(uint2*)&lP[w][l16][cb * 16 + quad * 4] = pk;   // 4 consecutive keys
    }

    // P·V : P A-frag (same-wave LDS round trip, no barrier)
    v8s PA0 = *(const v8s*)&lP[w][l16][quad * 8];
    v8s PA1 = *(const v8s*)&lP[w][l16][quad * 8 + 32];
    #pragma unroll
    for (int cb = 0; cb < 4; cb++){
      v8s vb0 = *(const v8s*)(vB0 + cb * 1024);
      v8s vb1 = *(const v8s*)(vB1 + cb * 1024);
      O[cb] = __builtin_amdgcn_mfma_f32_16x16x32_bf16(PA0, vb0, O[cb], 0, 0, 0);
      O[cb] = __builtin_amdgcn_mfma_f32_16x16x32_bf16(PA1, vb1, O[cb], 0, 0, 0);
    }
    __syncthreads();    // reads done before next stage overwrites
  }

  rsum += __shfl_xor(rsum, 16, 64);
  rsum += __shfl_xor(rsum, 32, 64);

  if (direct){
    float inv[4];
    #pragma unroll
    for (int r = 0; r < 4; r++)
      inv[r] = 1.0f / __shfl(rsum, quad * 4 + r, 64);
    #pragma unroll
    for (int cb = 0; cb < 4; cb++)
      #pragma unroll
      for (int r = 0; r < 4; r++){
        int row = q0 + m0 + quad * 4 + r;
        ctx[(b * NN + row) * 64 + cb * 16 + l16] = f2bf(O[cb][r] * inv[r]);
      }
  } else {
    int bf = (b * 64 + qt) * 4 + sp;
    if (quad == 0) lipart[bf * 64 + m0 + l16] = rsum;
    float* Ob = Opart + (size_t)bf * 4096;
    #pragma unroll
    for (int cb = 0; cb < 4; cb++)
      #pragma unroll
      for (int r = 0; r < 4; r++)
        Ob[(m0 + quad * 4 + r) * 64 + cb * 16 + l16] = O[cb][r];
  }
}

// ---------------------------------------------------------------------------
// Kernel 2b: combine split-K partials -> bf16 ctx.  float4 per thread.
// ---------------------------------------------------------------------------
__global__ __launch_bounds__(256) void reduce_kernel(
    const float* __restrict__ Opart,
    const float* __restrict__ lipart,
    unsigned short* __restrict__ ctx)
{
  int i4 = blockIdx.x * 256 + threadIdx.x;      // 524288 total (x4 elements)
  int bqt = i4 >> 10;                           // (b*64+qt), 1024 vec4 each
  int rem = (i4 & 1023) << 2;                   // element offset within 4096
  int rl  = rem >> 6;                           // row within 64
  const float* Ob  = Opart  + (size_t)bqt * 4 * 4096;
  const float* lib = lipart + bqt * 4 * 64;
  v4f s = *(const v4f*)(Ob + rem);
  s = s + *(const v4f*)(Ob + 4096  + rem);
  s = s + *(const v4f*)(Ob + 8192  + rem);
  s = s + *(const v4f*)(Ob + 12288 + rem);
  float li = (lib[rl] + lib[64 + rl]) + (lib[128 + rl] + lib[192 + rl]);
  float inv = 1.0f / li;
  uint2 o; o.x = pkbf(s[0] * inv, s[1] * inv); o.y = pkbf(s[2] * inv, s[3] * inv);
  *(uint2*)(ctx + (size_t)bqt * 4096 + rem) = o;
}

// ---------------------------------------------------------------------------
// Kernel 3: out = gamma * ctx @ Wv + bv + x.  M=32768, K=64, N=512.
// ---------------------------------------------------------------------------
__global__ __launch_bounds__(256) void outproj_kernel(
    const unsigned short* __restrict__ ctx,
    const unsigned short* __restrict__ Wvt,  // [512][64] bf16
    const float* __restrict__ bv,
    const float* __restrict__ x,
    const float* __restrict__ gamma_p,
    float* __restrict__ out)
{
  __shared__ __align__(16) short lA[64][72];
  __shared__ __align__(16) short lB[128][72];
  int t = threadIdx.x;
  int w = t >> 6, lane = t & 63;
  int quad = lane >> 4, l16 = lane & 15;
  int rowbase = blockIdx.x * 64;
  int colbase = blockIdx.y * 128;
  float gamma = *gamma_p;

  #pragma unroll
  for (int r = 0; r < 2; r++){
    int chunk = t + r * 256;
    int row = chunk >> 3, c8 = chunk & 7;
    *(v8s*)&lA[row][c8 * 8] = *(const v8s*)(ctx + (rowbase + row) * 64 + c8 * 8);
  }
  #pragma unroll
  for (int r = 0; r < 4; r++){
    int chunk = t + r * 256;
    int row = chunk >> 3, c8 = chunk & 7;
    *(v8s*)&lB[row][c8 * 8] = *(const v8s*)(Wvt + (colbase + row) * 64 + c8 * 8);
  }
  __syncthreads();
  int m0 = w * 16;
  v8s A0 = *(const v8s*)&lA[m0 + l16][quad * 8];
  v8s A1 = *(const v8s*)&lA[m0 + l16][quad * 8 + 32];
  v4f acc[8];
  #pragma unroll
  for (int cb = 0; cb < 8; cb++){
    v8s b0 = *(const v8s*)&lB[cb * 16 + l16][quad * 8];
    v8s b1 = *(const v8s*)&lB[cb * 16 + l16][quad * 8 + 32];
    v4f z = (v4f){0.f, 0.f, 0.f, 0.f};
    z = __builtin_amdgcn_mfma_f32_16x16x32_bf16(A0, b0, z, 0, 0, 0);
    acc[cb] = __builtin_amdgcn_mfma_f32_16x16x32_bf16(A1, b1, z, 0, 0, 0);
  }
  #pragma unroll
  for (int cb = 0; cb < 8; cb++){
    int col = colbase + cb * 16 + l16;
    float bvv = bv[col];
    #pragma unroll
    for (int r = 0; r < 4; r++){
      int gr = rowbase + m0 + quad * 4 + r;
      out[gr * 512 + col] = gamma * acc[cb][r] + bvv + x[gr * 512 + col];
    }
  }
}

// ---------------------------------------------------------------------------
extern "C" void kernel_launch(void* const* d_in, const int* in_sizes, int n_in,
                              void* d_out, int out_size, void* d_ws, size_t ws_size,
                              hipStream_t stream) {
  const float* x   = (const float*)d_in[0];
  const float* Wf  = (const float*)d_in[1];
  const float* bf_ = (const float*)d_in[2];
  const float* Wg  = (const float*)d_in[3];
  const float* bg  = (const float*)d_in[4];
  const float* Wh  = (const float*)d_in[5];
  const float* bh  = (const float*)d_in[6];
  const float* Wv  = (const float*)d_in[7];
  const float* bv  = (const float*)d_in[8];
  const float* gam = (const float*)d_in[9];
  float* out = (float*)d_out;

  // workspace map (bytes):
  //   Wt   @ 0         (196608)
  //   Wvt  @ 196608    (65536)
  //   f    @ 262144    (4194304)
  //   g    @ 4456448   (4194304)
  //   ht   @ 8650752   (4194304)
  //   ctx  @ 12845056  (4194304)
  //   Opart @ 17039360 (33554432)   split-K partials
  //   lipart@ 50593792 (524288)     total 51118080 (~48.8 MiB)
  char* ws = (char*)d_ws;
  unsigned short* Wt  = (unsigned short*)(ws);
  unsigned short* Wvt = (unsigned short*)(ws + 196608);
  unsigned short* f   = (unsigned short*)(ws + 262144);
  unsigned short* g   = (unsigned short*)(ws + 4456448);
  unsigned short* ht  = (unsigned short*)(ws + 8650752);
  unsigned short* ctx = (unsigned short*)(ws + 12845056);
  float* Opart  = (float*)(ws + 17039360);
  float* lipart = (float*)(ws + 50593792);

  transpose_w<<<512, 256, 0, stream>>>(Wf, Wg, Wh, Wv, Wt, Wvt);
  proj_kernel<<<512, 256, 0, stream>>>(x, Wt, bf_, bg, bh, f, g, ht);

  bool split = (ws_size >= (size_t)51118080);
  if (split){
    flash_kernel<<<dim3(64, 4, 8), 256, 0, stream>>>(f, g, ht, Opart, lipart, ctx, 16, 0);
    reduce_kernel<<<2048, 256, 0, stream>>>(Opart, lipart, ctx);
  } else {
    flash_kernel<<<dim3(64, 1, 8), 256, 0, stream>>>(f, g, ht, nullptr, nullptr, ctx, 64, 1);
  }
  outproj_kernel<<<dim3(512, 4), 256, 0, stream>>>(ctx, Wvt, bv, x, gam, out);
}